// Round 1
// baseline (614.886 us; speedup 1.0000x reference)
//
#include <hip/hip_runtime.h>

typedef __attribute__((ext_vector_type(8))) short short8;
typedef __attribute__((ext_vector_type(4))) float floatx4;
typedef unsigned int u32;
typedef unsigned short u16;

// ---------- helpers ----------
__device__ __forceinline__ u16 f2bf(float f) {
  u32 u = __float_as_uint(f);
  u += 0x7FFFu + ((u >> 16) & 1u);   // RNE
  return (u16)(u >> 16);
}

typedef const __attribute__((address_space(1))) u32* gp1_t;
typedef __attribute__((address_space(3))) u32* lp3_t;

__device__ __forceinline__ void gld16(const void* g, void* l) {
  // async global -> LDS, 16B per lane; LDS dest is wave-uniform base + lane*16
  __builtin_amdgcn_global_load_lds((gp1_t)g, (lp3_t)l, 16, 0, 0);
}

// ---------- kernel 1: x fp32 -> bf16 ----------
__global__ __launch_bounds__(256) void xconv(const float* __restrict__ x,
                                             u16* __restrict__ xb, long long n4) {
  long long i = (long long)blockIdx.x * 256 + threadIdx.x;
  if (i >= n4) return;
  float4 v = ((const float4*)x)[i];
  ushort4 o;
  o.x = f2bf(v.x); o.y = f2bf(v.y); o.z = f2bf(v.z); o.w = f2bf(v.w);
  ((ushort4*)xb)[i] = o;
}

// ---------- kernel 2: dequant int4 -> Wt[n][k] bf16 (transposed) ----------
// qweight (IN/8, OUT): nibble s of qweight[kk][n] is W[kk*8+s][n]
__global__ __launch_bounds__(256) void dequant(
    const int* __restrict__ qw, const int* __restrict__ qz,
    const int* __restrict__ qs, const float* __restrict__ qsz,
    const float* __restrict__ qss, const int* __restrict__ gidx,
    u16* __restrict__ Wt, int IN, int OUT) {
  int lane = threadIdx.x & 63;
  int wave = threadIdx.x >> 6;
  int kk = blockIdx.y * 64 + lane;          // packed-k row (lanes along kk -> coalesced writes)
  int n0 = blockIdx.x * 64 + wave * 16;
  int kbase = kk * 8;
  int g[8];
  float z0[8], ss[8];
#pragma unroll
  for (int s = 0; s < 8; ++s) {
    g[s] = gidx[kbase + s];
    z0[s] = qsz[g[s]];
    ss[s] = qss[g[s]];
  }
  for (int i = 0; i < 16; ++i) {
    int n = n0 + i;
    int w32 = qw[(size_t)kk * OUT + n];     // strided across lanes but L1-resident
    u16 o[8];
#pragma unroll
    for (int s = 0; s < 8; ++s) {
      int gs = g[s];
      int zq = ((qz[(size_t)gs * (OUT >> 3) + (n >> 3)] >> (4 * (n & 7))) & 15) + 1;
      float sc = ((float)qs[(size_t)gs * OUT + n] - z0[s]) * ss[s];
      int w = (w32 >> (4 * s)) & 15;
      o[s] = f2bf((float)(w - zq) * sc);
    }
    uint4 pk;
    pk.x = (u32)o[0] | ((u32)o[1] << 16);
    pk.y = (u32)o[2] | ((u32)o[3] << 16);
    pk.z = (u32)o[4] | ((u32)o[5] << 16);
    pk.w = (u32)o[6] | ((u32)o[7] << 16);
    *(uint4*)(Wt + (size_t)n * IN + kbase) = pk;   // coalesced 16B/lane
  }
}

// ---------- kernel 3: bf16 GEMM, C = A(MxK) * Bt(NxK)^T ----------
// m97 structure: 128x128 tile, BK=32, 4 waves (2x2), 4x4 MFMA 16x16x32 per wave
__global__ __launch_bounds__(256) void gemm(const u16* __restrict__ A,
                                            const u16* __restrict__ Bt,
                                            float* __restrict__ C,
                                            int M, int N, int K) {
  __shared__ u16 As[128 * 32];
  __shared__ u16 Bs[128 * 32];
  const int tid = threadIdx.x;
  const int lane = tid & 63;
  const int wave = tid >> 6;
  const int wm = wave & 1, wn = wave >> 1;
  const int lr = lane & 15, quad = lane >> 4;
  const int m0 = blockIdx.y * 128, n0 = blockIdx.x * 128;

  floatx4 acc[4][4] = {};

  // staging map: wave w fills rows [w*32, w*32+32); lane covers 16B chunks
  const int srow = wave * 32 + (lane >> 2);
  const int scol = (lane & 3) * 8;
  const u16* aSrc = A + (size_t)(m0 + srow) * K + scol;
  const u16* bSrc = Bt + (size_t)(n0 + srow) * K + scol;
  u16* aDst = &As[srow * 32 + scol];
  u16* bDst = &Bs[srow * 32 + scol];

  for (int k0 = 0; k0 < K; k0 += 32) {
    __syncthreads();
    gld16(aSrc + k0, aDst);
    gld16(aSrc + (size_t)16 * K + k0, aDst + 16 * 32);
    gld16(bSrc + k0, bDst);
    gld16(bSrc + (size_t)16 * K + k0, bDst + 16 * 32);
    __syncthreads();   // compiler emits s_waitcnt vmcnt(0) before s_barrier

    short8 aF[4], bF[4];
#pragma unroll
    for (int t = 0; t < 4; ++t) {
      aF[t] = *(const short8*)&As[(wm * 64 + t * 16 + lr) * 32 + quad * 8];
      bF[t] = *(const short8*)&Bs[(wn * 64 + t * 16 + lr) * 32 + quad * 8];
    }
#pragma unroll
    for (int mt = 0; mt < 4; ++mt)
#pragma unroll
      for (int nt = 0; nt < 4; ++nt)
        acc[mt][nt] = __builtin_amdgcn_mfma_f32_16x16x32_bf16(
            aF[mt], bF[nt], acc[mt][nt], 0, 0, 0);
  }

  // epilogue: C/D layout col=lane&15, row=quad*4+reg
#pragma unroll
  for (int mt = 0; mt < 4; ++mt)
#pragma unroll
    for (int nt = 0; nt < 4; ++nt)
#pragma unroll
      for (int r = 0; r < 4; ++r) {
        int row = m0 + wm * 64 + mt * 16 + quad * 4 + r;
        int col = n0 + wn * 64 + nt * 16 + lr;
        C[(size_t)row * N + col] = acc[mt][nt][r];
      }
}

// ---------- fallback: naive dequant-on-the-fly (ws too small) ----------
__global__ void naive(const float* __restrict__ x, const int* __restrict__ qw,
                      const int* __restrict__ qz, const int* __restrict__ qs,
                      const float* __restrict__ qsz, const float* __restrict__ qss,
                      const int* __restrict__ gidx, float* __restrict__ out,
                      int M, int N, int K) {
  int n = blockIdx.x * 64 + (threadIdx.x & 63);
  int m = blockIdx.y * 4 + (threadIdx.x >> 6);
  if (n >= N || m >= M) return;
  float acc = 0.f;
  for (int kk = 0; kk < K / 8; ++kk) {
    int w32 = qw[(size_t)kk * N + n];
#pragma unroll
    for (int s = 0; s < 8; ++s) {
      int k = kk * 8 + s;
      int g = gidx[k];
      int zq = ((qz[(size_t)g * (N >> 3) + (n >> 3)] >> (4 * (n & 7))) & 15) + 1;
      float sc = ((float)qs[(size_t)g * N + n] - qsz[g]) * qss[g];
      acc += x[(size_t)m * K + k] * ((float)((w32 >> (4 * s)) & 15) - (float)zq) * sc;
    }
  }
  out[(size_t)m * N + n] = acc;
}

extern "C" void kernel_launch(void* const* d_in, const int* in_sizes, int n_in,
                              void* d_out, int out_size, void* d_ws, size_t ws_size,
                              hipStream_t stream) {
  const float* x = (const float*)d_in[0];
  const int* qw = (const int*)d_in[1];
  const int* qz = (const int*)d_in[2];
  const int* qs = (const int*)d_in[3];
  const float* qsz = (const float*)d_in[4];
  const float* qss = (const float*)d_in[5];
  const int* gidx = (const int*)d_in[6];
  const int IN = in_sizes[6];                                   // 4096
  const int OUT = (int)(((long long)in_sizes[1] * 8) / IN);     // 4096
  const int M = in_sizes[0] / IN;                               // 8192
  float* out = (float*)d_out;

  size_t bytesW = (size_t)IN * OUT * 2;
  size_t bytesX = (size_t)M * IN * 2;
  bool fast = (ws_size >= bytesW + bytesX) && (M % 128 == 0) && (OUT % 128 == 0) &&
              (IN % 64 == 0) && ((IN / 8) % 64 == 0) && (OUT % 64 == 0) &&
              ((size_t)M * IN % 4 == 0);

  if (fast) {
    u16* Wt = (u16*)d_ws;
    u16* Xb = (u16*)((char*)d_ws + bytesW);
    long long n4 = (long long)M * IN / 4;
    int cb = (int)((n4 + 255) / 256);
    xconv<<<cb, 256, 0, stream>>>(x, Xb, n4);
    dequant<<<dim3(OUT / 64, (IN / 8) / 64), 256, 0, stream>>>(qw, qz, qs, qsz, qss,
                                                              gidx, Wt, IN, OUT);
    gemm<<<dim3(OUT / 128, M / 128), 256, 0, stream>>>(Xb, Wt, out, M, OUT, IN);
  } else {
    naive<<<dim3((OUT + 63) / 64, (M + 3) / 4), 256, 0, stream>>>(
        x, qw, qz, qs, qsz, qss, gidx, out, M, OUT, IN);
  }
}

// Round 2
// 582.254 us; speedup vs baseline: 1.0560x; 1.0560x over previous
//
#include <hip/hip_runtime.h>

typedef __attribute__((ext_vector_type(8))) short short8;
typedef __attribute__((ext_vector_type(4))) float floatx4;
typedef unsigned int u32;
typedef unsigned short u16;

// ---------- helpers ----------
__device__ __forceinline__ u16 f2bf(float f) {
  u32 u = __float_as_uint(f);
  u += 0x7FFFu + ((u >> 16) & 1u);   // RNE
  return (u16)(u >> 16);
}

typedef const __attribute__((address_space(1))) u32* gp1_t;
typedef __attribute__((address_space(3))) u32* lp3_t;

__device__ __forceinline__ void gld16(const void* g, void* l) {
  // async global -> LDS, 16B per lane; LDS dest is wave-uniform base + lane*16
  __builtin_amdgcn_global_load_lds((gp1_t)g, (lp3_t)l, 16, 0, 0);
}

// ---------- kernel 1: x fp32 -> bf16 ----------
__global__ __launch_bounds__(256) void xconv(const float* __restrict__ x,
                                             u16* __restrict__ xb, long long n4) {
  long long i = (long long)blockIdx.x * 256 + threadIdx.x;
  if (i >= n4) return;
  float4 v = ((const float4*)x)[i];
  ushort4 o;
  o.x = f2bf(v.x); o.y = f2bf(v.y); o.z = f2bf(v.z); o.w = f2bf(v.w);
  ((ushort4*)xb)[i] = o;
}

// ---------- kernel 2: dequant int4 -> Wt[n][k] bf16 (transposed) ----------
// Coalesced rewrite: lanes along n; one group per (block, wave); each thread
// handles 4 consecutive packed rows (k span 32 = one group) for one column n.
// qw/qz/qs loads fully coalesced; stores are 4x16B per row completing 64B
// lines (L2 write-combines).
__global__ __launch_bounds__(256) void dequant(
    const int* __restrict__ qw, const int* __restrict__ qz,
    const int* __restrict__ qs, const float* __restrict__ qsz,
    const float* __restrict__ qss, const int* __restrict__ gidx,
    u16* __restrict__ Wt, int IN, int OUT) {
  const int n = blockIdx.x * 64 + (threadIdx.x & 63);
  const int w = threadIdx.x >> 6;            // 0..3
  const int k0 = blockIdx.y * 128 + w * 32;  // one 32-wide group per wave-slice
  const int g = gidx[k0];                    // wave-uniform scalar load
  const int kk0 = k0 >> 3;                   // 4 packed rows
  const int zq = ((qz[(size_t)g * (OUT >> 3) + (n >> 3)] >> (4 * (n & 7))) & 15) + 1;
  const float sc = ((float)qs[(size_t)g * OUT + n] - qsz[g]) * qss[g];
  u16* dst = Wt + (size_t)n * IN + k0;
#pragma unroll
  for (int j = 0; j < 4; ++j) {
    const int w32 = qw[(size_t)(kk0 + j) * OUT + n];   // coalesced across lanes
    u16 o[8];
#pragma unroll
    for (int s = 0; s < 8; ++s)
      o[s] = f2bf((float)(((w32 >> (4 * s)) & 15) - zq) * sc);
    uint4 pk;
    pk.x = (u32)o[0] | ((u32)o[1] << 16);
    pk.y = (u32)o[2] | ((u32)o[3] << 16);
    pk.z = (u32)o[4] | ((u32)o[5] << 16);
    pk.w = (u32)o[6] | ((u32)o[7] << 16);
    *(uint4*)(dst + j * 8) = pk;
  }
}

// ---------- kernel 3: bf16 GEMM, C = A(MxK) * Bt(NxK)^T ----------
// m97 structure: 128x128 tile, BK=32, 4 waves (2x2), 4x4 MFMA 16x16x32 per wave.
// LDS XOR swizzle: LDS(row, chunk) holds global (row, chunk ^ (row&3)); applied
// by permuting the *global source* column per lane (gld16 LDS dst must stay
// base+lane*16). ds_read applies the same XOR -> 8-way bank conflict drops to
// the b128 4-way floor.
__global__ __launch_bounds__(256) void gemm(const u16* __restrict__ A,
                                            const u16* __restrict__ Bt,
                                            float* __restrict__ C,
                                            int M, int N, int K) {
  __shared__ u16 As[128 * 32];
  __shared__ u16 Bs[128 * 32];
  const int tid = threadIdx.x;
  const int lane = tid & 63;
  const int wave = tid >> 6;
  const int wm = wave & 1, wn = wave >> 1;
  const int lr = lane & 15, quad = lane >> 4;
  const int m0 = blockIdx.y * 128, n0 = blockIdx.x * 128;

  floatx4 acc[4][4] = {};

  // staging map: wave w fills rows [w*32, w*32+32); lane covers 16B chunks
  const int srow = wave * 32 + (lane >> 2);
  const int scolL = (lane & 3) * 8;                          // LDS col (contiguous)
  const int scolG = ((lane & 3) ^ ((lane >> 2) & 3)) * 8;    // swizzled source col
  const u16* aSrc = A + (size_t)(m0 + srow) * K + scolG;
  const u16* bSrc = Bt + (size_t)(n0 + srow) * K + scolG;
  u16* aDst = &As[srow * 32 + scolL];
  u16* bDst = &Bs[srow * 32 + scolL];

  // fragment read column with matching XOR (row&3 == lr&3 for all t)
  const int rcol = (quad ^ (lr & 3)) * 8;

  for (int k0 = 0; k0 < K; k0 += 32) {
    __syncthreads();
    gld16(aSrc + k0, aDst);
    gld16(aSrc + (size_t)16 * K + k0, aDst + 16 * 32);
    gld16(bSrc + k0, bDst);
    gld16(bSrc + (size_t)16 * K + k0, bDst + 16 * 32);
    __syncthreads();   // compiler emits s_waitcnt vmcnt(0) before s_barrier

    short8 aF[4], bF[4];
#pragma unroll
    for (int t = 0; t < 4; ++t) {
      aF[t] = *(const short8*)&As[(wm * 64 + t * 16 + lr) * 32 + rcol];
      bF[t] = *(const short8*)&Bs[(wn * 64 + t * 16 + lr) * 32 + rcol];
    }
#pragma unroll
    for (int mt = 0; mt < 4; ++mt)
#pragma unroll
      for (int nt = 0; nt < 4; ++nt)
        acc[mt][nt] = __builtin_amdgcn_mfma_f32_16x16x32_bf16(
            aF[mt], bF[nt], acc[mt][nt], 0, 0, 0);
  }

  // epilogue: C/D layout col=lane&15, row=quad*4+reg
#pragma unroll
  for (int mt = 0; mt < 4; ++mt)
#pragma unroll
    for (int nt = 0; nt < 4; ++nt)
#pragma unroll
      for (int r = 0; r < 4; ++r) {
        int row = m0 + wm * 64 + mt * 16 + quad * 4 + r;
        int col = n0 + wn * 64 + nt * 16 + lr;
        C[(size_t)row * N + col] = acc[mt][nt][r];
      }
}

// ---------- fallback: naive dequant-on-the-fly (ws too small) ----------
__global__ void naive(const float* __restrict__ x, const int* __restrict__ qw,
                      const int* __restrict__ qz, const int* __restrict__ qs,
                      const float* __restrict__ qsz, const float* __restrict__ qss,
                      const int* __restrict__ gidx, float* __restrict__ out,
                      int M, int N, int K) {
  int n = blockIdx.x * 64 + (threadIdx.x & 63);
  int m = blockIdx.y * 4 + (threadIdx.x >> 6);
  if (n >= N || m >= M) return;
  float acc = 0.f;
  for (int kk = 0; kk < K / 8; ++kk) {
    int w32 = qw[(size_t)kk * N + n];
#pragma unroll
    for (int s = 0; s < 8; ++s) {
      int k = kk * 8 + s;
      int g = gidx[k];
      int zq = ((qz[(size_t)g * (N >> 3) + (n >> 3)] >> (4 * (n & 7))) & 15) + 1;
      float sc = ((float)qs[(size_t)g * N + n] - qsz[g]) * qss[g];
      acc += x[(size_t)m * K + k] * ((float)((w32 >> (4 * s)) & 15) - (float)zq) * sc;
    }
  }
  out[(size_t)m * N + n] = acc;
}

extern "C" void kernel_launch(void* const* d_in, const int* in_sizes, int n_in,
                              void* d_out, int out_size, void* d_ws, size_t ws_size,
                              hipStream_t stream) {
  const float* x = (const float*)d_in[0];
  const int* qw = (const int*)d_in[1];
  const int* qz = (const int*)d_in[2];
  const int* qs = (const int*)d_in[3];
  const float* qsz = (const float*)d_in[4];
  const float* qss = (const float*)d_in[5];
  const int* gidx = (const int*)d_in[6];
  const int IN = in_sizes[6];                                   // 4096
  const int OUT = (int)(((long long)in_sizes[1] * 8) / IN);     // 4096
  const int M = in_sizes[0] / IN;                               // 8192
  float* out = (float*)d_out;

  size_t bytesW = (size_t)IN * OUT * 2;
  size_t bytesX = (size_t)M * IN * 2;
  bool fast = (ws_size >= bytesW + bytesX) && (M % 128 == 0) && (OUT % 128 == 0) &&
              (IN % 128 == 0) && (OUT % 64 == 0) && ((size_t)M * IN % 4 == 0);

  if (fast) {
    u16* Wt = (u16*)d_ws;
    u16* Xb = (u16*)((char*)d_ws + bytesW);
    long long n4 = (long long)M * IN / 4;
    int cb = (int)((n4 + 255) / 256);
    xconv<<<cb, 256, 0, stream>>>(x, Xb, n4);
    dequant<<<dim3(OUT / 64, IN / 128), 256, 0, stream>>>(qw, qz, qs, qsz, qss,
                                                          gidx, Wt, IN, OUT);
    gemm<<<dim3(OUT / 128, M / 128), 256, 0, stream>>>(Xb, Wt, out, M, OUT, IN);
  } else {
    naive<<<dim3((OUT + 63) / 64, (M + 3) / 4), 256, 0, stream>>>(
        x, qw, qz, qs, qsz, qss, gidx, out, M, OUT, IN);
  }
}

// Round 3
// 552.249 us; speedup vs baseline: 1.1134x; 1.0543x over previous
//
#include <hip/hip_runtime.h>

typedef __attribute__((ext_vector_type(8))) short short8;
typedef __attribute__((ext_vector_type(4))) float floatx4;
typedef unsigned int u32;
typedef unsigned short u16;

// ---------- helpers ----------
__device__ __forceinline__ u16 f2bf(float f) {
  u32 u = __float_as_uint(f);
  u += 0x7FFFu + ((u >> 16) & 1u);   // RNE
  return (u16)(u >> 16);
}

typedef const __attribute__((address_space(1))) u32* gp1_t;
typedef __attribute__((address_space(3))) u32* lp3_t;

__device__ __forceinline__ void gld16(const void* g, void* l) {
  // async global -> LDS, 16B per lane; LDS dest is wave-uniform base + lane*16
  __builtin_amdgcn_global_load_lds((gp1_t)g, (lp3_t)l, 16, 0, 0);
}

// ---------- kernel 1: x fp32 -> bf16 ----------
__global__ __launch_bounds__(256) void xconv(const float* __restrict__ x,
                                             u16* __restrict__ xb, long long n4) {
  long long i = (long long)blockIdx.x * 256 + threadIdx.x;
  if (i >= n4) return;
  float4 v = ((const float4*)x)[i];
  ushort4 o;
  o.x = f2bf(v.x); o.y = f2bf(v.y); o.z = f2bf(v.z); o.w = f2bf(v.w);
  ((ushort4*)xb)[i] = o;
}

// ---------- kernel 2: dequant int4 -> Wt[n][k] bf16 (transposed) ----------
// lanes along n (coalesced qw/qz/qs); one group(32) per wave-slice; 4 packed
// rows per thread -> each thread completes a 64B line of Wt.
__global__ __launch_bounds__(256) void dequant(
    const int* __restrict__ qw, const int* __restrict__ qz,
    const int* __restrict__ qs, const float* __restrict__ qsz,
    const float* __restrict__ qss, const int* __restrict__ gidx,
    u16* __restrict__ Wt, int IN, int OUT) {
  const int n = blockIdx.x * 64 + (threadIdx.x & 63);
  const int w = threadIdx.x >> 6;            // 0..3
  const int k0 = blockIdx.y * 128 + w * 32;  // one 32-wide group per wave-slice
  const int g = gidx[k0];                    // uniform across wave
  const int kk0 = k0 >> 3;                   // 4 packed rows
  const int zq = ((qz[(size_t)g * (OUT >> 3) + (n >> 3)] >> (4 * (n & 7))) & 15) + 1;
  const float sc = ((float)qs[(size_t)g * OUT + n] - qsz[g]) * qss[g];
  u16* dst = Wt + (size_t)n * IN + k0;
#pragma unroll
  for (int j = 0; j < 4; ++j) {
    const int w32 = qw[(size_t)(kk0 + j) * OUT + n];   // coalesced across lanes
    u16 o[8];
#pragma unroll
    for (int s = 0; s < 8; ++s)
      o[s] = f2bf((float)(((w32 >> (4 * s)) & 15) - zq) * sc);
    uint4 pk;
    pk.x = (u32)o[0] | ((u32)o[1] << 16);
    pk.y = (u32)o[2] | ((u32)o[3] << 16);
    pk.z = (u32)o[4] | ((u32)o[5] << 16);
    pk.w = (u32)o[6] | ((u32)o[7] << 16);
    *(uint4*)(dst + j * 8) = pk;
  }
}

// ---------- kernel 3: bf16 GEMM, C = A(MxK) * Bt(NxK)^T ----------
// 128x128 tile, BK=64 (32 MFMA per barrier pair), 4 waves (2x2), 4x4 MFMA
// 16x16x32 per wave per k-half. Row stride 128B == 32 banks, so an XOR-8
// chunk swizzle is mandatory: LDS(row, c) holds Global(row, c ^ (row&7));
// applied on the global source column (gld16 LDS dst is base+lane*16 fixed),
// undone on the ds_read address -> 2 lanes/bank (free).
__global__ __launch_bounds__(256) void gemm(const u16* __restrict__ A,
                                            const u16* __restrict__ Bt,
                                            float* __restrict__ C,
                                            int M, int N, int K) {
  __shared__ u16 As[128 * 64];
  __shared__ u16 Bs[128 * 64];
  const int tid = threadIdx.x;
  const int lane = tid & 63;
  const int wave = tid >> 6;
  const int wm = wave & 1, wn = wave >> 1;
  const int lr = lane & 15, quad = lane >> 4;
  const int m0 = blockIdx.y * 128, n0 = blockIdx.x * 128;

  floatx4 acc[4][4] = {};

  // staging: wave w covers rows [w*32, w*32+32); 4 gld16 calls per operand,
  // call c covers rows w*32+c*8 .. +8, lane -> (row = +lane>>3, chunk = lane&7)
  const int srowB = (lane >> 3);                      // 0..7 within call
  const int schunk = (lane & 7) ^ srowB;              // swizzled source chunk
  const int rowA0 = wave * 32;
  const u16* aSrc = A + (size_t)(m0 + rowA0 + srowB) * K + schunk * 8;
  const u16* bSrc = Bt + (size_t)(n0 + rowA0 + srowB) * K + schunk * 8;
  u16* aDst = &As[rowA0 * 64];
  u16* bDst = &Bs[rowA0 * 64];
  const size_t rstep = (size_t)8 * K;                 // 8 rows per call

  // fragment read: row = wm*64 + t*16 + lr; chunk q = quad + 4*h, read
  // LDS chunk q ^ (lr&7)
  const int rx = lr & 7;

  for (int k0 = 0; k0 < K; k0 += 64) {
    __syncthreads();
#pragma unroll
    for (int c = 0; c < 4; ++c) {
      gld16(aSrc + c * rstep + k0, aDst + c * 8 * 64);
      gld16(bSrc + c * rstep + k0, bDst + c * 8 * 64);
    }
    __syncthreads();   // compiler emits s_waitcnt vmcnt(0) before s_barrier

#pragma unroll
    for (int h = 0; h < 2; ++h) {
      short8 aF[4], bF[4];
      const int rc = ((quad + 4 * h) ^ rx) * 8;
#pragma unroll
      for (int t = 0; t < 4; ++t) {
        aF[t] = *(const short8*)&As[(wm * 64 + t * 16 + lr) * 64 + rc];
        bF[t] = *(const short8*)&Bs[(wn * 64 + t * 16 + lr) * 64 + rc];
      }
#pragma unroll
      for (int mt = 0; mt < 4; ++mt)
#pragma unroll
        for (int nt = 0; nt < 4; ++nt)
          acc[mt][nt] = __builtin_amdgcn_mfma_f32_16x16x32_bf16(
              aF[mt], bF[nt], acc[mt][nt], 0, 0, 0);
    }
  }

  // epilogue: C/D layout col=lane&15, row=quad*4+reg
#pragma unroll
  for (int mt = 0; mt < 4; ++mt)
#pragma unroll
    for (int nt = 0; nt < 4; ++nt)
#pragma unroll
      for (int r = 0; r < 4; ++r) {
        int row = m0 + wm * 64 + mt * 16 + quad * 4 + r;
        int col = n0 + wn * 64 + nt * 16 + lr;
        C[(size_t)row * N + col] = acc[mt][nt][r];
      }
}

// ---------- fallback: naive dequant-on-the-fly (ws too small) ----------
__global__ void naive(const float* __restrict__ x, const int* __restrict__ qw,
                      const int* __restrict__ qz, const int* __restrict__ qs,
                      const float* __restrict__ qsz, const float* __restrict__ qss,
                      const int* __restrict__ gidx, float* __restrict__ out,
                      int M, int N, int K) {
  int n = blockIdx.x * 64 + (threadIdx.x & 63);
  int m = blockIdx.y * 4 + (threadIdx.x >> 6);
  if (n >= N || m >= M) return;
  float acc = 0.f;
  for (int kk = 0; kk < K / 8; ++kk) {
    int w32 = qw[(size_t)kk * N + n];
#pragma unroll
    for (int s = 0; s < 8; ++s) {
      int k = kk * 8 + s;
      int g = gidx[k];
      int zq = ((qz[(size_t)g * (N >> 3) + (n >> 3)] >> (4 * (n & 7))) & 15) + 1;
      float sc = ((float)qs[(size_t)g * N + n] - qsz[g]) * qss[g];
      acc += x[(size_t)m * K + k] * ((float)((w32 >> (4 * s)) & 15) - (float)zq) * sc;
    }
  }
  out[(size_t)m * N + n] = acc;
}

extern "C" void kernel_launch(void* const* d_in, const int* in_sizes, int n_in,
                              void* d_out, int out_size, void* d_ws, size_t ws_size,
                              hipStream_t stream) {
  const float* x = (const float*)d_in[0];
  const int* qw = (const int*)d_in[1];
  const int* qz = (const int*)d_in[2];
  const int* qs = (const int*)d_in[3];
  const float* qsz = (const float*)d_in[4];
  const float* qss = (const float*)d_in[5];
  const int* gidx = (const int*)d_in[6];
  const int IN = in_sizes[6];                                   // 4096
  const int OUT = (int)(((long long)in_sizes[1] * 8) / IN);     // 4096
  const int M = in_sizes[0] / IN;                               // 8192
  float* out = (float*)d_out;

  size_t bytesW = (size_t)IN * OUT * 2;
  size_t bytesX = (size_t)M * IN * 2;
  bool fast = (ws_size >= bytesW + bytesX) && (M % 128 == 0) && (OUT % 128 == 0) &&
              (IN % 128 == 0) && ((size_t)M * IN % 4 == 0);

  if (fast) {
    u16* Wt = (u16*)d_ws;
    u16* Xb = (u16*)((char*)d_ws + bytesW);
    long long n4 = (long long)M * IN / 4;
    int cb = (int)((n4 + 255) / 256);
    xconv<<<cb, 256, 0, stream>>>(x, Xb, n4);
    dequant<<<dim3(OUT / 64, IN / 128), 256, 0, stream>>>(qw, qz, qs, qsz, qss,
                                                          gidx, Wt, IN, OUT);
    gemm<<<dim3(OUT / 128, M / 128), 256, 0, stream>>>(Xb, Wt, out, M, OUT, IN);
  } else {
    naive<<<dim3((OUT + 63) / 64, (M + 3) / 4), 256, 0, stream>>>(
        x, qw, qz, qs, qsz, qss, gidx, out, M, OUT, IN);
  }
}